// Round 6
// baseline (84.083 us; speedup 1.0000x reference)
//
#include <hip/hip_runtime.h>

#define NBINS 49
#define NCH   256
#define FH    256
#define FW    256
#define HWSZ  (FH * FW)
#define TD    64

typedef float f4 __attribute__((ext_vector_type(4)));

// ---------------- shared geometry: EXACT f32 replication of reference ----------------
// Verified absmax = 0.0 in R1-R5.
__device__ __forceinline__ void bin_geom(const float* __restrict__ bx, int tid,
                                         int& oTL, int& oTR, int& oBL, int& oBR,
                                         float& wlt, float& wrt, float& wrb, float& wlb)
{
    float cx  = __fmul_rn(bx[0], 0.25f);
    float cy  = __fmul_rn(bx[1], 0.25f);
    float w   = __fmul_rn(bx[2], 0.25f);
    float h   = __fmul_rn(bx[3], 0.25f);
    float ang = __fmul_rn(bx[4], 0.017453292519943295f);
    float ca = (float)cos((double)ang);
    float sa = (float)sin((double)ang);
    float Sx = __fdiv_rn(w, 7.0f);
    float Sy = __fdiv_rn(h, 7.0f);
    const float dx = -3.5f, dy = -3.5f;
    float M00 = __fmul_rn(ca, Sx);
    float M01 = __fmul_rn(sa, Sy);
    float M02 = __fadd_rn(__fadd_rn(__fmul_rn(M00, dx), __fmul_rn(M01, dy)), cx);
    float nsa = -sa;
    float M10 = __fmul_rn(nsa, Sx);
    float M11 = __fmul_rn(ca, Sy);
    float M12 = __fadd_rn(__fadd_rn(__fmul_rn(M10, dx), __fmul_rn(M11, dy)), cy);

    int ph = tid / 7, pw = tid % 7;
    float minX = 1e30f, maxX = -1e30f, minY = 1e30f, maxY = -1e30f;
    #pragma unroll
    for (int o0 = 0; o0 < 2; ++o0) {
        #pragma unroll
        for (int o1 = 0; o1 < 2; ++o1) {
            float px = (float)(pw + o0);
            float py = (float)(ph + o1);
            float Xc = __fadd_rn(__fadd_rn(__fmul_rn(M00, px), __fmul_rn(M01, py)), M02);
            float Yc = __fadd_rn(__fadd_rn(__fmul_rn(M10, px), __fmul_rn(M11, py)), M12);
            minX = fminf(minX, Xc); maxX = fmaxf(maxX, Xc);
            minY = fminf(minY, Yc); maxY = fmaxf(maxY, Yc);
        }
    }
    float leftMost   = fmaxf(rintf(minX), 0.0f);
    float rightMost  = fminf(rintf(maxX), (float)(FW - 1));
    float topMost    = fmaxf(rintf(minY), 0.0f);
    float bottomMost = fminf(rintf(maxY), (float)(FH - 1));
    float bcx = __fmul_rn(__fadd_rn(leftMost, rightMost), 0.5f);
    float bcy = __fmul_rn(__fadd_rn(topMost, bottomMost), 0.5f);
    float fl = floorf(bcx), ft = floorf(bcy);
    int l   = (int)fl;
    int r   = (int)ceilf(bcx);
    int t   = (int)ft;
    int btm = (int)ceilf(bcy);
    float rx = __fsub_rn(bcx, fl);   // exactly 0.0 or 0.5
    float ry = __fsub_rn(bcy, ft);

    bool vl = (unsigned)l   < (unsigned)FW;
    bool vr = (unsigned)r   < (unsigned)FW;
    bool vt = (unsigned)t   < (unsigned)FH;
    bool vb = (unsigned)btm < (unsigned)FH;
    int xl = min(max(l, 0), FW - 1), xr = min(max(r, 0), FW - 1);
    int yt = min(max(t, 0), FH - 1), yb = min(max(btm, 0), FH - 1);

    oTL = yt * FW + xl;
    oTR = yt * FW + xr;
    oBL = yb * FW + xl;
    oBR = yb * FW + xr;
    float w_lt = (1.0f - rx) * (1.0f - ry);
    float w_rt = rx * (1.0f - ry);
    float w_rb = rx * ry;
    float w_lb = (1.0f - rx) * ry;
    wlt = (vt && vl) ? w_lt : 0.0f;
    wrt = (vt && vr) ? w_rt : 0.0f;
    wrb = (vb && vr) ? w_rb : 0.0f;
    wlb = (vb && vl) ? w_lb : 0.0f;
}

// ---------------- transpose one 64x64 tile (R1-proven body) ----------------
// load -> sync -> store; caller inserts a sync before reusing the tile.
__device__ __forceinline__ void transpose_tile(
    const float* __restrict__ in, float* __restrict__ outT,
    int bz, int hwt, int ct, int t, float (*tile)[TD + 1])
{
    const int hw0 = hwt * TD;
    const int c0  = ct * TD;
    const float* A = in   + (size_t)bz * NCH * HWSZ;
    float*       B = outT + (size_t)bz * HWSZ * NCH;

    const int hwq = (t & 15) * 4;   // 0..60
    const int cr  = t >> 4;         // 0..15
    #pragma unroll
    for (int k = 0; k < 4; ++k) {
        int c = cr + k * 16;
        f4 v = __builtin_nontemporal_load(
                   (const f4*)&A[(size_t)(c0 + c) * HWSZ + hw0 + hwq]);
        tile[c][hwq + 0] = v.x;
        tile[c][hwq + 1] = v.y;
        tile[c][hwq + 2] = v.z;
        tile[c][hwq + 3] = v.w;
    }
    __syncthreads();
    const int cq  = (t & 15) * 4;
    const int hwr = t >> 4;
    #pragma unroll
    for (int k = 0; k < 4; ++k) {
        int hw = hwr + k * 16;
        f4 v;
        v.x = tile[cq + 0][hw];
        v.y = tile[cq + 1][hw];
        v.z = tile[cq + 2][hw];
        v.w = tile[cq + 3][hw];
        *(f4*)&B[(size_t)(hw0 + hw) * NCH + c0 + cq] = v;
    }
}

// ---------------- pool one ROI (R1/R4-proven body) ----------------
// smem layout: [0,25088)=stage, [25088,26656)=geometry. 26,656 B total.
#define SMEM_BYTES 26656
__device__ __forceinline__ void pool_roi(
    const float* __restrict__ xt, const float* __restrict__ boxes,
    float* __restrict__ out, int roi, int tid, char* smem)
{
    float* s_stage = (float*)smem;                 // 6272 floats
    int*   s_oTL   = (int*)(smem + 25088);
    int*   s_oTR   = s_oTL + NBINS;
    int*   s_oBL   = s_oTR + NBINS;
    int*   s_oBR   = s_oBL + NBINS;
    float* s_wlt   = (float*)(s_oBR + NBINS);
    float* s_wrt   = s_wlt + NBINS;
    float* s_wrb   = s_wrt + NBINS;
    float* s_wlb   = s_wrb + NBINS;

    const int b = roi >> 9;

    if (tid < NBINS) {
        int oTL, oTR, oBL, oBR; float wlt, wrt, wrb, wlb;
        bin_geom(boxes + roi * 5, tid, oTL, oTR, oBL, oBR, wlt, wrt, wrb, wlb);
        s_oTL[tid] = oTL;  s_oTR[tid] = oTR;
        s_oBL[tid] = oBL;  s_oBR[tid] = oBR;
        s_wlt[tid] = wlt;  s_wrt[tid] = wrt;
        s_wrb[tid] = wrb;  s_wlb[tid] = wlb;
    }
    __syncthreads();

    const float* fb = xt + (size_t)b * HWSZ * NCH;
    float p[NBINS];
    #pragma unroll
    for (int bin = 0; bin < NBINS; ++bin) {
        // wave-uniform point offsets -> SGPRs (SALU addr math, saddr loads)
        int oTL = __builtin_amdgcn_readfirstlane(s_oTL[bin]);
        int oTR = __builtin_amdgcn_readfirstlane(s_oTR[bin]);
        int oBL = __builtin_amdgcn_readfirstlane(s_oBL[bin]);
        int oBR = __builtin_amdgcn_readfirstlane(s_oBR[bin]);
        float wlt = s_wlt[bin], wrt = s_wrt[bin], wrb = s_wrb[bin], wlb = s_wlb[bin];
        float lt = fb[(size_t)oTL * NCH + tid];   // 64 lanes -> 256B contiguous
        float rt = fb[(size_t)oTR * NCH + tid];
        float lb = fb[(size_t)oBL * NCH + tid];
        float rb = fb[(size_t)oBR * NCH + tid];
        float v = lt * wlt + rt * wrt + rb * wrb + lb * wlb;
        p[bin] = fmaxf(v, 0.0f);
    }

    // coalesced epilogue: two 128-channel halves through LDS (R4 sequence).
    // stage is disjoint from geometry -> no barrier before the first stage.
    f4* out4 = (f4*)(out + (size_t)roi * NCH * NBINS);
    const f4* lds4 = (const f4*)s_stage;
    const int HV4 = 128 * NBINS / 4;  // 1568 f4 per half

    if ((tid >> 7) == 0) {                         // waves 0,1: channels 0-127
        float* dst = s_stage + tid * NBINS;        // stride 49: conflict-free
        #pragma unroll
        for (int bin = 0; bin < NBINS; ++bin) dst[bin] = p[bin];
    }
    __syncthreads();
    for (int j = tid; j < HV4; j += 256)
        __builtin_nontemporal_store(lds4[j], &out4[j]);
    __syncthreads();
    if ((tid >> 7) == 1) {                         // waves 2,3: channels 128-255
        float* dst = s_stage + (tid & 127) * NBINS;
        #pragma unroll
        for (int bin = 0; bin < NBINS; ++bin) dst[bin] = p[bin];
    }
    __syncthreads();
    for (int j = tid; j < HV4; j += 256)
        __builtin_nontemporal_store(lds4[j], &out4[HV4 + j]);
}

// ---------------- K1: transpose batch 0 (full machine) ----------------
__global__ __launch_bounds__(256) void k1_transpose_b0(
    const float* __restrict__ in, float* __restrict__ outT)
{
    __shared__ float tile[TD][TD + 1];
    transpose_tile(in, outT, 0, blockIdx.x, blockIdx.y, threadIdx.x, tile);
}

// ---------------- K2: pool batch0  ||  transpose batch1 ----------------
// R6: the pool is LLC/latency-limited (~27us, only ~100MB HBM) while the
// transpose saturates HBM. Running pool(b0) concurrently with transpose(b1)
// fills the HBM slack the serial schedule wasted. Role by blockIdx
// (block-uniform): 0-511 pool ROIs 0-511; 512-1023 transpose 8 b1-tiles each.
__global__ __launch_bounds__(256) void k2_pool0_transpose1(
    const float* __restrict__ x, float* __restrict__ xt,
    const float* __restrict__ boxes, float* __restrict__ out)
{
    __shared__ __align__(16) char smem[SMEM_BYTES];   // union: tile 16.6KB / pool 26.7KB
    if (blockIdx.x < 512) {
        pool_roi(xt, boxes, out, blockIdx.x, threadIdx.x, smem);
    } else {
        float (*tile)[TD + 1] = (float (*)[TD + 1])smem;
        const int base = (blockIdx.x - 512) * 8;
        #pragma unroll 1
        for (int k = 0; k < 8; ++k) {
            const int t   = base + k;        // 0..4095
            const int ct  = t >> 10;         // 0..3
            const int hwt = t & 1023;
            transpose_tile(x, xt, 1, hwt, ct, threadIdx.x, tile);
            __syncthreads();                 // tile reuse across iterations
        }
    }
}

// ---------------- K3: pool batch 1 ----------------
__global__ __launch_bounds__(256) void k3_pool_b1(
    const float* __restrict__ xt, const float* __restrict__ boxes,
    float* __restrict__ out)
{
    __shared__ __align__(16) char smem[SMEM_BYTES];
    pool_roi(xt, boxes, out, 512 + blockIdx.x, threadIdx.x, smem);
}

// ---------------- fallback: proven R0 single-pass kernel ----------------
__global__ __launch_bounds__(256) void rroi_pool_chw(
    const float* __restrict__ x, const float* __restrict__ boxes, float* __restrict__ out)
{
    __shared__ int   s_l[NBINS], s_r[NBINS], s_t[NBINS], s_b[NBINS];
    __shared__ float s_rx[NBINS], s_ry[NBINS];
    const int roi = blockIdx.x, tid = threadIdx.x, b = roi >> 9;
    if (tid < NBINS) {
        const float* bx = boxes + roi * 5;
        float cx  = __fmul_rn(bx[0], 0.25f);
        float cy  = __fmul_rn(bx[1], 0.25f);
        float w   = __fmul_rn(bx[2], 0.25f);
        float h   = __fmul_rn(bx[3], 0.25f);
        float ang = __fmul_rn(bx[4], 0.017453292519943295f);
        float ca = (float)cos((double)ang);
        float sa = (float)sin((double)ang);
        float Sx = __fdiv_rn(w, 7.0f);
        float Sy = __fdiv_rn(h, 7.0f);
        const float dx = -3.5f, dy = -3.5f;
        float M00 = __fmul_rn(ca, Sx);
        float M01 = __fmul_rn(sa, Sy);
        float M02 = __fadd_rn(__fadd_rn(__fmul_rn(M00, dx), __fmul_rn(M01, dy)), cx);
        float nsa = -sa;
        float M10 = __fmul_rn(nsa, Sx);
        float M11 = __fmul_rn(ca, Sy);
        float M12 = __fadd_rn(__fadd_rn(__fmul_rn(M10, dx), __fmul_rn(M11, dy)), cy);
        int ph = tid / 7, pw = tid % 7;
        float minX = 1e30f, maxX = -1e30f, minY = 1e30f, maxY = -1e30f;
        #pragma unroll
        for (int o0 = 0; o0 < 2; ++o0)
            #pragma unroll
            for (int o1 = 0; o1 < 2; ++o1) {
                float px = (float)(pw + o0);
                float py = (float)(ph + o1);
                float Xc = __fadd_rn(__fadd_rn(__fmul_rn(M00, px), __fmul_rn(M01, py)), M02);
                float Yc = __fadd_rn(__fadd_rn(__fmul_rn(M10, px), __fmul_rn(M11, py)), M12);
                minX = fminf(minX, Xc); maxX = fmaxf(maxX, Xc);
                minY = fminf(minY, Yc); maxY = fmaxf(maxY, Yc);
            }
        float leftMost   = fmaxf(rintf(minX), 0.0f);
        float rightMost  = fminf(rintf(maxX), (float)(FW - 1));
        float topMost    = fmaxf(rintf(minY), 0.0f);
        float bottomMost = fminf(rintf(maxY), (float)(FH - 1));
        float bcx = __fmul_rn(__fadd_rn(leftMost, rightMost), 0.5f);
        float bcy = __fmul_rn(__fadd_rn(topMost, bottomMost), 0.5f);
        float fl = floorf(bcx), ft = floorf(bcy);
        s_l[tid] = (int)fl;  s_r[tid] = (int)ceilf(bcx);
        s_t[tid] = (int)ft;  s_b[tid] = (int)ceilf(bcy);
        s_rx[tid] = __fsub_rn(bcx, fl);
        s_ry[tid] = __fsub_rn(bcy, ft);
    }
    __syncthreads();
    const float* featb = x + (size_t)b * NCH * HWSZ;
    float* outr = out + (size_t)roi * NCH * NBINS;
    for (int i = tid; i < NCH * NBINS; i += 256) {
        int c = i / NBINS, bin = i - c * NBINS;
        int l = s_l[bin], r = s_r[bin], t = s_t[bin], btm = s_b[bin];
        float rx = s_rx[bin], ry = s_ry[bin];
        const float* fc = featb + (size_t)c * HWSZ;
        bool vl = (unsigned)l < (unsigned)FW, vr = (unsigned)r < (unsigned)FW;
        bool vt = (unsigned)t < (unsigned)FH, vb = (unsigned)btm < (unsigned)FH;
        int lc = min(max(l, 0), FW - 1), rc = min(max(r, 0), FW - 1);
        int tc = min(max(t, 0), FH - 1), bc = min(max(btm, 0), FH - 1);
        float lt = (vt && vl) ? fc[tc * FW + lc] : 0.0f;
        float rt = (vt && vr) ? fc[tc * FW + rc] : 0.0f;
        float lb = (vb && vl) ? fc[bc * FW + lc] : 0.0f;
        float rb = (vb && vr) ? fc[bc * FW + rc] : 0.0f;
        float w_lt = (1.0f - rx) * (1.0f - ry);
        float w_rt = rx * (1.0f - ry);
        float w_rb = rx * ry;
        float w_lb = (1.0f - rx) * ry;
        float v = lt * w_lt + rt * w_rt + rb * w_rb + lb * w_lb;
        outr[i] = fmaxf(v, 0.0f);
    }
}

extern "C" void kernel_launch(void* const* d_in, const int* in_sizes, int n_in,
                              void* d_out, int out_size, void* d_ws, size_t ws_size,
                              hipStream_t stream) {
    const float* x     = (const float*)d_in[0];
    const float* boxes = (const float*)d_in[1];
    float* out = (float*)d_out;
    (void)in_sizes; (void)n_in; (void)out_size;

    const size_t need = (size_t)2 * NCH * HWSZ * sizeof(float);  // 128 MB
    if (ws_size >= need) {
        float* xt = (float*)d_ws;
        k1_transpose_b0<<<dim3(HWSZ / TD, NCH / TD, 1), dim3(256), 0, stream>>>(x, xt);
        k2_pool0_transpose1<<<dim3(1024), dim3(256), 0, stream>>>(x, xt, boxes, out);
        k3_pool_b1<<<dim3(512), dim3(256), 0, stream>>>(xt, boxes, out);
    } else {
        rroi_pool_chw<<<dim3(1024), dim3(256), 0, stream>>>(x, boxes, out);
    }
}

// Round 7
// 70.839 us; speedup vs baseline: 1.1870x; 1.1870x over previous
//
#include <hip/hip_runtime.h>

#define NBINS 49
#define NCH   256
#define FH    256
#define FW    256
#define HWSZ  (FH * FW)

typedef float f4 __attribute__((ext_vector_type(4)));

// ---------------- pass 1: transpose (B,C,H,W) -> (B,H*W,C) ----------------
// R3 LESSON: bitmap write-predication lost (occupancy ~69%, atomics+divergence).
// R5 LESSON: slab/LLC-reuse pipeline lost (launch tails, no write-back saving).
// R6 LESSON: in-kernel overlap with the pool lost (serial-tile MLP loss + LLC
// contention evicting xt under the pool). Plain full-machine transpose is at
// the 268MB streaming floor (~41us @ ~6.5TB/s measured).
#define TD 64
__global__ __launch_bounds__(256) void transpose_chw_hwc(
    const float* __restrict__ in,   // (2, 256, 65536)
    float* __restrict__ outT)       // (2, 65536, 256)
{
    __shared__ float tile[TD][TD + 1];
    const int t   = threadIdx.x;
    const int hw0 = blockIdx.x * TD;
    const int c0  = blockIdx.y * TD;
    const int bz  = blockIdx.z;
    const float* A = in   + (size_t)bz * NCH * HWSZ;
    float*       B = outT + (size_t)bz * HWSZ * NCH;

    // read: coalesced along HW (x streamed once -> nontemporal)
    const int hwq = (t & 15) * 4;   // 0..60
    const int cr  = t >> 4;         // 0..15
    #pragma unroll
    for (int k = 0; k < 4; ++k) {
        int c = cr + k * 16;
        f4 v = __builtin_nontemporal_load(
                   (const f4*)&A[(size_t)(c0 + c) * HWSZ + hw0 + hwq]);
        tile[c][hwq + 0] = v.x;
        tile[c][hwq + 1] = v.y;
        tile[c][hwq + 2] = v.z;
        tile[c][hwq + 3] = v.w;
    }
    __syncthreads();
    // write: coalesced along C (re-read by pool pass -> normal cached store)
    const int cq  = (t & 15) * 4;
    const int hwr = t >> 4;
    #pragma unroll
    for (int k = 0; k < 4; ++k) {
        int hw = hwr + k * 16;
        f4 v;
        v.x = tile[cq + 0][hw];
        v.y = tile[cq + 1][hw];
        v.z = tile[cq + 2][hw];
        v.w = tile[cq + 3][hw];
        *(f4*)&B[(size_t)(hw0 + hw) * NCH + c0 + cq] = v;
    }
}

// ---------------- pass 2: pool on NHWC, lane = channel ----------------
// R1: coalesced LDS-staged epilogue (write amp 5.3x -> 1x), 199.6 -> 71.0 us.
// R2 LESSON: gather loads must stay UNCONDITIONAL (latency/MLP).
// R4 LESSON: gather is BW-bound at the LLC, not latency-bound (deeper batching
// neutral); zero-weight corners are duplicate ADDRESSES (rx==0 => l==r), so
// caches already dedupe them.
__global__ __launch_bounds__(256, 4) void rroi_pool_nhwc(
    const float* __restrict__ xt,     // (2, 65536, 256)
    const float* __restrict__ boxes,  // (1024, 5)
    float* __restrict__ out)          // (1024, 256, 7, 7)
{
    __shared__ int   s_oTL[NBINS], s_oTR[NBINS], s_oBL[NBINS], s_oBR[NBINS];
    __shared__ float s_wlt[NBINS], s_wrt[NBINS], s_wrb[NBINS], s_wlb[NBINS];
    __shared__ __align__(16) float s_stage[128 * NBINS];   // 25,088 B

    const int roi = blockIdx.x;
    const int tid = threadIdx.x;      // = channel
    const int b   = roi >> 9;

    if (tid < NBINS) {
        const float* bx = boxes + roi * 5;
        // --- exact f32 replication of reference geometry (absmax=0.0 verified) ---
        float cx  = __fmul_rn(bx[0], 0.25f);
        float cy  = __fmul_rn(bx[1], 0.25f);
        float w   = __fmul_rn(bx[2], 0.25f);
        float h   = __fmul_rn(bx[3], 0.25f);
        float ang = __fmul_rn(bx[4], 0.017453292519943295f);
        float ca = (float)cos((double)ang);
        float sa = (float)sin((double)ang);
        float Sx = __fdiv_rn(w, 7.0f);
        float Sy = __fdiv_rn(h, 7.0f);
        const float dx = -3.5f, dy = -3.5f;
        float M00 = __fmul_rn(ca, Sx);
        float M01 = __fmul_rn(sa, Sy);
        float M02 = __fadd_rn(__fadd_rn(__fmul_rn(M00, dx), __fmul_rn(M01, dy)), cx);
        float nsa = -sa;
        float M10 = __fmul_rn(nsa, Sx);
        float M11 = __fmul_rn(ca, Sy);
        float M12 = __fadd_rn(__fadd_rn(__fmul_rn(M10, dx), __fmul_rn(M11, dy)), cy);

        int ph = tid / 7, pw = tid % 7;
        float minX = 1e30f, maxX = -1e30f, minY = 1e30f, maxY = -1e30f;
        #pragma unroll
        for (int o0 = 0; o0 < 2; ++o0) {
            #pragma unroll
            for (int o1 = 0; o1 < 2; ++o1) {
                float px = (float)(pw + o0);
                float py = (float)(ph + o1);
                float Xc = __fadd_rn(__fadd_rn(__fmul_rn(M00, px), __fmul_rn(M01, py)), M02);
                float Yc = __fadd_rn(__fadd_rn(__fmul_rn(M10, px), __fmul_rn(M11, py)), M12);
                minX = fminf(minX, Xc); maxX = fmaxf(maxX, Xc);
                minY = fminf(minY, Yc); maxY = fmaxf(maxY, Yc);
            }
        }
        float leftMost   = fmaxf(rintf(minX), 0.0f);
        float rightMost  = fminf(rintf(maxX), (float)(FW - 1));
        float topMost    = fmaxf(rintf(minY), 0.0f);
        float bottomMost = fminf(rintf(maxY), (float)(FH - 1));
        float bcx = __fmul_rn(__fadd_rn(leftMost, rightMost), 0.5f);
        float bcy = __fmul_rn(__fadd_rn(topMost, bottomMost), 0.5f);
        float fl = floorf(bcx), ft = floorf(bcy);
        int l   = (int)fl;
        int r   = (int)ceilf(bcx);
        int t   = (int)ft;
        int btm = (int)ceilf(bcy);
        float rx = __fsub_rn(bcx, fl);   // exactly 0.0 or 0.5
        float ry = __fsub_rn(bcy, ft);

        bool vl = (unsigned)l   < (unsigned)FW;
        bool vr = (unsigned)r   < (unsigned)FW;
        bool vt = (unsigned)t   < (unsigned)FH;
        bool vb = (unsigned)btm < (unsigned)FH;
        int xl = min(max(l, 0), FW - 1), xr = min(max(r, 0), FW - 1);
        int yt = min(max(t, 0), FH - 1), yb = min(max(btm, 0), FH - 1);

        s_oTL[tid] = yt * FW + xl;
        s_oTR[tid] = yt * FW + xr;
        s_oBL[tid] = yb * FW + xl;
        s_oBR[tid] = yb * FW + xr;
        float w_lt = (1.0f - rx) * (1.0f - ry);
        float w_rt = rx * (1.0f - ry);
        float w_rb = rx * ry;
        float w_lb = (1.0f - rx) * ry;
        s_wlt[tid] = (vt && vl) ? w_lt : 0.0f;
        s_wrt[tid] = (vt && vr) ? w_rt : 0.0f;
        s_wrb[tid] = (vb && vr) ? w_rb : 0.0f;
        s_wlb[tid] = (vb && vl) ? w_lb : 0.0f;
    }
    __syncthreads();

    const float* fb = xt + (size_t)b * HWSZ * NCH;
    float p[NBINS];
    // deep-batched gather: 13 bins (52 loads) per group, all indices
    // compile-time after unroll (rule: no runtime-indexed arrays -> scratch).
    #pragma unroll
    for (int g = 0; g < NBINS; g += 13) {
        const int GN = (g + 13 <= NBINS) ? 13 : (NBINS - g);
        float lt[13], rt[13], lb[13], rb[13];
        #pragma unroll
        for (int k = 0; k < 13; ++k) {
            if (k < GN) {
                const int bin = g + k;
                // wave-uniform point offsets -> SGPRs (SALU addr, saddr loads)
                int oTL = __builtin_amdgcn_readfirstlane(s_oTL[bin]);
                int oTR = __builtin_amdgcn_readfirstlane(s_oTR[bin]);
                int oBL = __builtin_amdgcn_readfirstlane(s_oBL[bin]);
                int oBR = __builtin_amdgcn_readfirstlane(s_oBR[bin]);
                lt[k] = fb[(size_t)oTL * NCH + tid];   // 64 lanes -> 256B contiguous
                rt[k] = fb[(size_t)oTR * NCH + tid];
                lb[k] = fb[(size_t)oBL * NCH + tid];
                rb[k] = fb[(size_t)oBR * NCH + tid];
            }
        }
        #pragma unroll
        for (int k = 0; k < 13; ++k) {
            if (k < GN) {
                const int bin = g + k;
                float v = lt[k] * s_wlt[bin] + rt[k] * s_wrt[bin]
                        + rb[k] * s_wrb[bin] + lb[k] * s_wlb[bin];
                p[bin] = fmaxf(v, 0.0f);
            }
        }
    }

    // ---- coalesced epilogue: two 128-channel halves through LDS ----
    // per-ROI output block = 256*49 dwords, linear index c*49+bin.
    // s_stage is disjoint from the geometry arrays, so no barrier is needed
    // between the gather loop and the first stage write (3 barriers total).
    f4* out4 = (f4*)(out + (size_t)roi * NCH * NBINS);
    const f4* lds4 = (const f4*)s_stage;
    const int HV4 = 128 * NBINS / 4;  // 1568 f4 per half (25,088 B, 16B-aligned)

    if ((tid >> 7) == 0) {                         // waves 0,1: channels 0-127
        float* dst = s_stage + tid * NBINS;        // stride 49: odd -> conflict-free
        #pragma unroll
        for (int bin = 0; bin < NBINS; ++bin) dst[bin] = p[bin];
    }
    __syncthreads();
    for (int j = tid; j < HV4; j += 256)
        __builtin_nontemporal_store(lds4[j], &out4[j]);
    __syncthreads();
    if ((tid >> 7) == 1) {                         // waves 2,3: channels 128-255
        float* dst = s_stage + (tid & 127) * NBINS;
        #pragma unroll
        for (int bin = 0; bin < NBINS; ++bin) dst[bin] = p[bin];
    }
    __syncthreads();
    for (int j = tid; j < HV4; j += 256)
        __builtin_nontemporal_store(lds4[j], &out4[HV4 + j]);
}

// ---------------- fallback: proven R0 single-pass kernel ----------------
__global__ __launch_bounds__(256) void rroi_pool_chw(
    const float* __restrict__ x, const float* __restrict__ boxes, float* __restrict__ out)
{
    __shared__ int   s_l[NBINS], s_r[NBINS], s_t[NBINS], s_b[NBINS];
    __shared__ float s_rx[NBINS], s_ry[NBINS];
    const int roi = blockIdx.x, tid = threadIdx.x, b = roi >> 9;
    if (tid < NBINS) {
        const float* bx = boxes + roi * 5;
        float cx  = __fmul_rn(bx[0], 0.25f);
        float cy  = __fmul_rn(bx[1], 0.25f);
        float w   = __fmul_rn(bx[2], 0.25f);
        float h   = __fmul_rn(bx[3], 0.25f);
        float ang = __fmul_rn(bx[4], 0.017453292519943295f);
        float ca = (float)cos((double)ang);
        float sa = (float)sin((double)ang);
        float Sx = __fdiv_rn(w, 7.0f);
        float Sy = __fdiv_rn(h, 7.0f);
        const float dx = -3.5f, dy = -3.5f;
        float M00 = __fmul_rn(ca, Sx);
        float M01 = __fmul_rn(sa, Sy);
        float M02 = __fadd_rn(__fadd_rn(__fmul_rn(M00, dx), __fmul_rn(M01, dy)), cx);
        float nsa = -sa;
        float M10 = __fmul_rn(nsa, Sx);
        float M11 = __fmul_rn(ca, Sy);
        float M12 = __fadd_rn(__fadd_rn(__fmul_rn(M10, dx), __fmul_rn(M11, dy)), cy);
        int ph = tid / 7, pw = tid % 7;
        float minX = 1e30f, maxX = -1e30f, minY = 1e30f, maxY = -1e30f;
        #pragma unroll
        for (int o0 = 0; o0 < 2; ++o0)
            #pragma unroll
            for (int o1 = 0; o1 < 2; ++o1) {
                float px = (float)(pw + o0);
                float py = (float)(ph + o1);
                float Xc = __fadd_rn(__fadd_rn(__fmul_rn(M00, px), __fmul_rn(M01, py)), M02);
                float Yc = __fadd_rn(__fadd_rn(__fmul_rn(M10, px), __fmul_rn(M11, py)), M12);
                minX = fminf(minX, Xc); maxX = fmaxf(maxX, Xc);
                minY = fminf(minY, Yc); maxY = fmaxf(maxY, Yc);
            }
        float leftMost   = fmaxf(rintf(minX), 0.0f);
        float rightMost  = fminf(rintf(maxX), (float)(FW - 1));
        float topMost    = fmaxf(rintf(minY), 0.0f);
        float bottomMost = fminf(rintf(maxY), (float)(FH - 1));
        float bcx = __fmul_rn(__fadd_rn(leftMost, rightMost), 0.5f);
        float bcy = __fmul_rn(__fadd_rn(topMost, bottomMost), 0.5f);
        float fl = floorf(bcx), ft = floorf(bcy);
        s_l[tid] = (int)fl;  s_r[tid] = (int)ceilf(bcx);
        s_t[tid] = (int)ft;  s_b[tid] = (int)ceilf(bcy);
        s_rx[tid] = __fsub_rn(bcx, fl);
        s_ry[tid] = __fsub_rn(bcy, ft);
    }
    __syncthreads();
    const float* featb = x + (size_t)b * NCH * HWSZ;
    float* outr = out + (size_t)roi * NCH * NBINS;
    for (int i = tid; i < NCH * NBINS; i += 256) {
        int c = i / NBINS, bin = i - c * NBINS;
        int l = s_l[bin], r = s_r[bin], t = s_t[bin], btm = s_b[bin];
        float rx = s_rx[bin], ry = s_ry[bin];
        const float* fc = featb + (size_t)c * HWSZ;
        bool vl = (unsigned)l < (unsigned)FW, vr = (unsigned)r < (unsigned)FW;
        bool vt = (unsigned)t < (unsigned)FH, vb = (unsigned)btm < (unsigned)FH;
        int lc = min(max(l, 0), FW - 1), rc = min(max(r, 0), FW - 1);
        int tc = min(max(t, 0), FH - 1), bc = min(max(btm, 0), FH - 1);
        float lt = (vt && vl) ? fc[tc * FW + lc] : 0.0f;
        float rt = (vt && vr) ? fc[tc * FW + rc] : 0.0f;
        float lb = (vb && vl) ? fc[bc * FW + lc] : 0.0f;
        float rb = (vb && vr) ? fc[bc * FW + rc] : 0.0f;
        float w_lt = (1.0f - rx) * (1.0f - ry);
        float w_rt = rx * (1.0f - ry);
        float w_rb = rx * ry;
        float w_lb = (1.0f - rx) * ry;
        float v = lt * w_lt + rt * w_rt + rb * w_rb + lb * w_lb;
        outr[i] = fmaxf(v, 0.0f);
    }
}

extern "C" void kernel_launch(void* const* d_in, const int* in_sizes, int n_in,
                              void* d_out, int out_size, void* d_ws, size_t ws_size,
                              hipStream_t stream) {
    const float* x     = (const float*)d_in[0];
    const float* boxes = (const float*)d_in[1];
    float* out = (float*)d_out;
    (void)in_sizes; (void)n_in; (void)out_size;

    const size_t need = (size_t)2 * NCH * HWSZ * sizeof(float);  // 128 MB
    if (ws_size >= need) {
        float* xt = (float*)d_ws;
        transpose_chw_hwc<<<dim3(HWSZ / TD, NCH / TD, 2), dim3(256), 0, stream>>>(x, xt);
        rroi_pool_nhwc<<<dim3(1024), dim3(256), 0, stream>>>(xt, boxes, out);
    } else {
        rroi_pool_chw<<<dim3(1024), dim3(256), 0, stream>>>(x, boxes, out);
    }
}